// Round 18
// baseline (344.370 us; speedup 1.0000x reference)
//
#include <hip/hip_runtime.h>
#include <math.h>

typedef unsigned short u16;
typedef __attribute__((ext_vector_type(8))) _Float16 half8;
typedef __attribute__((ext_vector_type(4))) float f32x4;

#define NS 8192
#define MS 1024
#define CCH 512
#define CI 256
#define O3 768

// ---- fp16 helpers (bit-level storage as u16) ----
__device__ __forceinline__ float h2f(u16 u) {
    _Float16 h; *(u16*)&h = u; return (float)h;
}
__device__ __forceinline__ u16 f2h(float f) {
    _Float16 h = (_Float16)f; return *(u16*)&h;
}

// async global->LDS 16B
__device__ __forceinline__ void gld16(u16* lds, const u16* g) {
    __builtin_amdgcn_global_load_lds((const __attribute__((address_space(1))) void*)g,
                                     (__attribute__((address_space(3))) void*)lds,
                                     16, 0, 0);
}

// VALU cross-lane max via DPP (no LDS pipe). Butterfly covers 16-lane group.
template<int CTRL>
__device__ __forceinline__ float dppmax(float x) {
    union { float f; int i; } a, b;
    a.f = x;
    b.i = __builtin_amdgcn_update_dpp(a.i, a.i, CTRL, 0xF, 0xF, false);
    return fmaxf(a.f, b.f);
}
__device__ __forceinline__ float rowmax16(float x) {
    x = dppmax<0xB1>(x);     // quad_perm [1,0,3,2]
    x = dppmax<0x4E>(x);     // quad_perm [2,3,0,1]
    x = dppmax<0x141>(x);    // row_half_mirror
    x = dppmax<0x140>(x);    // row_mirror
    return x;
}

// ---------------------------------------------------------------------------
// prep: concat+convert weights to fp16
__global__ void prep_w(const float* __restrict__ tw, const float* __restrict__ tb,
                       const float* __restrict__ pw, const float* __restrict__ pb,
                       const float* __restrict__ gw, const float* __restrict__ gb,
                       const float* __restrict__ wzw,
                       u16* __restrict__ W3b, float* __restrict__ b3, u16* __restrict__ wzb) {
    int i = blockIdx.x * 256 + threadIdx.x;
    if (i < O3 * CCH) {
        int o = i >> 9, c = i & 511;
        float v = (o < 256) ? tw[o * 512 + c] : (o < 512) ? pw[(o - 256) * 512 + c]
                                              : gw[(o - 512) * 512 + c];
        W3b[i] = f2h(v);
    } else {
        int j = i - O3 * CCH;
        if (j < CCH * CI) wzb[j] = f2h(wzw[j]);
    }
    if (i < O3) b3[i] = (i < 256) ? tb[i] : (i < 512) ? pb[i - 256] : gb[i - 512];
}

// ---------------------------------------------------------------------------
// transpose x[b][c][n] fp32 -> xt[b][n][c] fp16   (tile 64c x 128n)
__global__ __launch_bounds__(256) void transpose_x(const float* __restrict__ x,
                                                   u16* __restrict__ xt) {
    __shared__ float tile[64][129];
    int b = blockIdx.z;
    int n0 = blockIdx.x * 128, c0 = blockIdx.y * 64;
    const float* xb = x + ((size_t)b * CCH + c0) * NS + n0;
    int t = threadIdx.x;
    #pragma unroll
    for (int i = 0; i < 32; ++i) {
        int idx = t + i * 256;
        int c = idx >> 7, n = idx & 127;
        tile[c][n] = xb[(size_t)c * NS + n];
    }
    __syncthreads();
    u16* xo = xt + ((size_t)b * NS + n0) * CCH + c0;
    #pragma unroll
    for (int i = 0; i < 16; ++i) {
        int idx = t + i * 256;
        int cp = idx & 31, n = idx >> 5;
        unsigned lo = f2h(tile[2 * cp][n]);
        unsigned hi = f2h(tile[2 * cp + 1][n]);
        *(unsigned*)(xo + (size_t)n * CCH + 2 * cp) = lo | (hi << 16);
    }
}

// ---------------------------------------------------------------------------
// proj GEMM with fused partial-pool epilogue (R12-proven, 256 threads).
// bx 0..1 (theta cols 0..255): dense write to projq[b][n][256].
// bx 2..5 (phi/g cols 256..767): 2x2 h/w max-pool in-register -> P1.
__global__ __launch_bounds__(256) void proj_gemm(
        const u16* __restrict__ A, const u16* __restrict__ Bm,
        const float* __restrict__ bias,
        u16* __restrict__ projq, u16* __restrict__ P1) {
    __shared__ u16 As[2][128 * 64];
    __shared__ u16 Bs[2][128 * 64];
    const int t = threadIdx.x;
    const int l = t & 63, w = t >> 6;
    const int wr = w >> 1, wc = w & 1;
    const int fr = l & 15, fq = l >> 4;

    const int nx = gridDim.x, ny = gridDim.y;
    int bid = blockIdx.x + nx * (blockIdx.y + ny * blockIdx.z);
    int cpx = (nx * ny * (int)gridDim.z) >> 3;
    int Wd = (bid & 7) * cpx + (bid >> 3);
    int bx = Wd % nx, rem = Wd / nx;
    int by = rem % ny, bz = rem / ny;

    const u16* gA = A + (size_t)bz * NS * CCH + (size_t)(by * 128) * CCH;
    const u16* gB = Bm + (size_t)(bx * 128) * CCH;

    f32x4 acc[4][4];
    #pragma unroll
    for (int m = 0; m < 4; ++m)
        #pragma unroll
        for (int n = 0; n < 4; ++n) acc[m][n] = (f32x4)0.f;

    #define STAGE_AB(buf, k0)                                                 \
        {                                                                     \
            _Pragma("unroll")                                                 \
            for (int i = 0; i < 4; ++i) {                                     \
                int cd = t + i * 256;                                         \
                int row = cd >> 3;                                            \
                int k8 = ((cd & 7) ^ (row & 7)) * 8;                          \
                int lbase = (cd & ~63) * 8;                                   \
                gld16(&As[buf][lbase], gA + (size_t)row * CCH + (k0) + k8);   \
                gld16(&Bs[buf][lbase], gB + (size_t)row * CCH + (k0) + k8);   \
            }                                                                 \
        }

    const int nk = CCH >> 6;   // 8
    STAGE_AB(0, 0);
    STAGE_AB(1, 64);

    for (int mt = 0; mt < nk; ++mt) {
        const int cur = mt & 1;
        if (mt == nk - 1) asm volatile("s_waitcnt vmcnt(0)" ::: "memory");
        else              asm volatile("s_waitcnt vmcnt(8)" ::: "memory");
        __builtin_amdgcn_sched_barrier(0);
        __builtin_amdgcn_s_barrier();

        half8 fa[4][2], fb[4][2];
        #pragma unroll
        for (int m = 0; m < 4; ++m)
            #pragma unroll
            for (int kk = 0; kk < 2; ++kk) {
                int ra = wr * 64 + m * 16 + fr;
                int rb = wc * 64 + m * 16 + fr;
                fa[m][kk] = *(const half8*)&As[cur][ra * 64 + ((((kk << 2) | fq)) ^ (ra & 7)) * 8];
                fb[m][kk] = *(const half8*)&Bs[cur][rb * 64 + ((((kk << 2) | fq)) ^ (rb & 7)) * 8];
            }
        __builtin_amdgcn_s_setprio(1);
        #pragma unroll
        for (int kk = 0; kk < 2; ++kk)
            #pragma unroll
            for (int m = 0; m < 4; ++m)
                #pragma unroll
                for (int n = 0; n < 4; ++n)
                    acc[m][n] = __builtin_amdgcn_mfma_f32_16x16x32_f16(
                        fa[m][kk], fb[n][kk], acc[m][n], 0, 0, 0);
        __builtin_amdgcn_s_setprio(0);

        __builtin_amdgcn_s_barrier();
        if (mt + 2 < nk) STAGE_AB(cur, (mt + 2) * 64);
    }
    #undef STAGE_AB

    const int ccol0 = bx * 128 + wc * 64;
    if (ccol0 < 256) {
        // theta: dense write projq[b][n][256]
        u16* gC = projq + (size_t)bz * NS * 256;
        const int crow0 = by * 128 + wr * 64;
        #pragma unroll
        for (int m = 0; m < 4; ++m)
            #pragma unroll
            for (int n = 0; n < 4; ++n) {
                int col = ccol0 + n * 16 + fr;
                float cb = bias[col];
                #pragma unroll
                for (int j = 0; j < 4; ++j) {
                    int row = crow0 + m * 16 + fq * 4 + j;
                    gC[(size_t)row * 256 + col] = f2h(acc[m][n][j] + cb);
                }
            }
    } else {
        // phi/g: 2x2 h/w-pool in-register -> P1[b][tt*256+h2*16+w2][c1]
        int tt = by >> 3;
        int h2 = ((by & 7) << 1) + wr;
        u16* gP = P1 + ((size_t)bz * 2048 + tt * 256 + h2 * 16) * 512;
        #pragma unroll
        for (int mh = 0; mh < 2; ++mh)
            #pragma unroll
            for (int n = 0; n < 4; ++n) {
                int col = ccol0 + n * 16 + fr;
                float cb = bias[col];
                int c1 = col - 256;
                #pragma unroll
                for (int jj = 0; jj < 2; ++jj) {
                    float mx = fmaxf(
                        fmaxf(acc[mh][n][2 * jj], acc[mh][n][2 * jj + 1]),
                        fmaxf(acc[mh + 2][n][2 * jj], acc[mh + 2][n][2 * jj + 1]));
                    int w2 = mh * 8 + fq * 2 + jj;
                    gP[(size_t)w2 * 512 + c1] = f2h(mx + cb);
                }
            }
    }
}

// ---------------------------------------------------------------------------
// pool2: finish t-pair max from P1 -> kb[b][m][ci], vg[b][ci][m] (coalesced)
__global__ __launch_bounds__(256) void pool2_kernel(const u16* __restrict__ P1,
                                                    u16* __restrict__ kb,
                                                    u16* __restrict__ vg) {
    int bid = blockIdx.x;                  // 8 * 4 * 4 = 128 blocks
    int b = bid >> 4, tp = (bid >> 2) & 3, hw0 = (bid & 3) * 64;
    int t = threadIdx.x;
    const u16* p0 = P1 + ((size_t)b * 2048 + (2 * tp) * 256 + hw0) * 512;
    const u16* p1 = p0 + 256 * 512;
    u16* kbb = kb + ((size_t)b * MS + tp * 256 + hw0) * CI + t;
    unsigned pack[32];
    #pragma unroll
    for (int mm = 0; mm < 64; ++mm) {
        size_t ro = (size_t)mm * 512;
        float kv = fmaxf(h2f(p0[ro + t]), h2f(p1[ro + t]));
        float vv = fmaxf(h2f(p0[ro + 256 + t]), h2f(p1[ro + 256 + t]));
        kbb[(size_t)mm * CI] = f2h(kv);
        unsigned hv = f2h(vv);
        if (mm & 1) pack[mm >> 1] |= hv << 16;
        else        pack[mm >> 1] = hv;
    }
    u16* dst = vg + ((size_t)b * CI + t) * MS + tp * 256 + hw0;
    #pragma unroll
    for (int i = 0; i < 8; ++i)
        *(uint4*)(dst + i * 8) = *(const uint4*)&pack[i * 4];
}

// ---------------------------------------------------------------------------
// NT GEMM (fp16, MFMA) — Wz stage (R12-proven). dbuf + counted vmcnt + T2.
// BIAS_MODE: 0 none, 1 by-row (fp32), 2 by-col (fp32)
template<int BIAS_MODE>
__global__ __launch_bounds__(256) void gemm_nt_f16(
        const u16* __restrict__ A, const u16* __restrict__ Bm,
        u16* __restrict__ C, const float* __restrict__ bias,
        int lda, int ldb, int ldc, int Ksize,
        size_t strideA, size_t strideB, size_t strideC) {
    __shared__ u16 As[2][128 * 64];
    __shared__ u16 Bs[2][128 * 64];
    const int t = threadIdx.x;
    const int l = t & 63, w = t >> 6;
    const int wr = w >> 1, wc = w & 1;
    const int fr = l & 15, fq = l >> 4;

    const int nx = gridDim.x, ny = gridDim.y;
    int bid = blockIdx.x + nx * (blockIdx.y + ny * blockIdx.z);
    int cpx = (nx * ny * (int)gridDim.z) >> 3;
    int Wd = (bid & 7) * cpx + (bid >> 3);
    int bx = Wd % nx, rem = Wd / nx;
    int by = rem % ny, bz = rem / ny;

    const u16* gA = A + (size_t)bz * strideA + (size_t)(by * 128) * lda;
    const u16* gB = Bm + (size_t)bz * strideB + (size_t)(bx * 128) * ldb;

    f32x4 acc[4][4];
    #pragma unroll
    for (int m = 0; m < 4; ++m)
        #pragma unroll
        for (int n = 0; n < 4; ++n) acc[m][n] = (f32x4)0.f;

    #define STAGE_AB(buf, k0)                                                 \
        {                                                                     \
            _Pragma("unroll")                                                 \
            for (int i = 0; i < 4; ++i) {                                     \
                int cd = t + i * 256;                                         \
                int row = cd >> 3;                                            \
                int k8 = ((cd & 7) ^ (row & 7)) * 8;                          \
                int lbase = (cd & ~63) * 8;                                   \
                gld16(&As[buf][lbase], gA + (size_t)row * lda + (k0) + k8);   \
                gld16(&Bs[buf][lbase], gB + (size_t)row * ldb + (k0) + k8);   \
            }                                                                 \
        }

    const int nk = Ksize >> 6;
    STAGE_AB(0, 0);
    STAGE_AB(1, 64);

    for (int mt = 0; mt < nk; ++mt) {
        const int cur = mt & 1;
        if (mt == nk - 1) asm volatile("s_waitcnt vmcnt(0)" ::: "memory");
        else              asm volatile("s_waitcnt vmcnt(8)" ::: "memory");
        __builtin_amdgcn_sched_barrier(0);
        __builtin_amdgcn_s_barrier();

        half8 fa[4][2], fb[4][2];
        #pragma unroll
        for (int m = 0; m < 4; ++m)
            #pragma unroll
            for (int kk = 0; kk < 2; ++kk) {
                int ra = wr * 64 + m * 16 + fr;
                int rb = wc * 64 + m * 16 + fr;
                fa[m][kk] = *(const half8*)&As[cur][ra * 64 + ((((kk << 2) | fq)) ^ (ra & 7)) * 8];
                fb[m][kk] = *(const half8*)&Bs[cur][rb * 64 + ((((kk << 2) | fq)) ^ (rb & 7)) * 8];
            }
        __builtin_amdgcn_s_setprio(1);
        #pragma unroll
        for (int kk = 0; kk < 2; ++kk)
            #pragma unroll
            for (int m = 0; m < 4; ++m)
                #pragma unroll
                for (int n = 0; n < 4; ++n)
                    acc[m][n] = __builtin_amdgcn_mfma_f32_16x16x32_f16(
                        fa[m][kk], fb[n][kk], acc[m][n], 0, 0, 0);
        __builtin_amdgcn_s_setprio(0);

        __builtin_amdgcn_s_barrier();
        if (mt + 2 < nk) STAGE_AB(cur, (mt + 2) * 64);
    }
    #undef STAGE_AB

    u16* gC = C + (size_t)bz * strideC;
    const int crow0 = by * 128 + wr * 64;
    const int ccol0 = bx * 128 + wc * 64;
    #pragma unroll
    for (int m = 0; m < 4; ++m) {
        #pragma unroll
        for (int n = 0; n < 4; ++n) {
            int col = ccol0 + n * 16 + fr;
            float cb = (BIAS_MODE == 2) ? bias[col] : 0.f;
            #pragma unroll
            for (int j = 0; j < 4; ++j) {
                int row = crow0 + m * 16 + fq * 4 + j;
                float v = acc[m][n][j] + cb;
                if (BIAS_MODE == 1) v += bias[row];
                gC[(size_t)row * ldc + col] = f2h(v);
            }
        }
    }
}

// ---------------------------------------------------------------------------
// Fused flash attention (R12-proven): 8 waves x 16 q-rows, m-tile 64,
// K/V dbuf, counted vmcnt, raw barriers, DPP max, ones-MFMA row-sums.
__global__ __launch_bounds__(512, 2) void attn_fused(
        const u16* __restrict__ projq, const u16* __restrict__ kb,
        const u16* __restrict__ vg, u16* __restrict__ y) {
    __shared__ u16 Ks[2][64 * 256];     // 2 x 32 KB
    __shared__ u16 Vs[2][256 * 64];     // 2 x 32 KB
    __shared__ u16 Ps[8][16][40];       // 10 KB

    int bid0 = blockIdx.x + 64 * blockIdx.y;
    int W = (bid0 & 7) * 64 + (bid0 >> 3);
    const int b = W >> 6;
    const int n0 = (W & 63) * 128;

    const int t = threadIdx.x;
    const int l = t & 63, w = t >> 6;
    const int fr = l & 15, fq = l >> 4;

    const u16* projb = projq + (size_t)b * NS * 256;
    const u16* kbb = kb + (size_t)b * MS * CI;
    const u16* vgb = vg + (size_t)b * CI * MS;

    half8 qf[8];
    {
        const u16* qrow = projb + (size_t)(n0 + w * 16 + fr) * 256 + fq * 8;
        #pragma unroll
        for (int kk = 0; kk < 8; ++kk)
            qf[kk] = *(const half8*)(qrow + kk * 32);
    }

    half8 ones;
    #pragma unroll
    for (int i = 0; i < 8; ++i) ones[i] = (_Float16)1.f;

    f32x4 accO[16];
    #pragma unroll
    for (int nf = 0; nf < 16; ++nf) accO[nf] = (f32x4)0.f;
    f32x4 accL = (f32x4)0.f;            // row sums via ones-MFMA
    float m_run[4];
    #pragma unroll
    for (int j = 0; j < 4; ++j) m_run[j] = -1e30f;

    #define STAGE_KV(buf, m0)                                                     \
        {                                                                         \
            _Pragma("unroll")                                                     \
            for (int i = 0; i < 4; ++i) {                                         \
                int c = t + i * 512;                                              \
                int lb = (c & ~63) << 3;                                          \
                int krow = c >> 5, kk8 = c & 31;                                  \
                gld16(&Ks[buf][lb],                                               \
                      kbb + (size_t)((m0) + krow) * CI + ((kk8 ^ (krow & 7)) << 3)); \
                int vrow = c >> 3, vk8 = c & 7;                                   \
                gld16(&Vs[buf][lb],                                               \
                      vgb + (size_t)vrow * MS + (m0) + ((vk8 ^ (vrow & 7)) << 3)); \
            }                                                                     \
        }

    STAGE_KV(0, 0);
    STAGE_KV(1, 64);

    for (int mt = 0; mt < 16; ++mt) {
        const int cur = mt & 1;
        if (mt == 15) asm volatile("s_waitcnt vmcnt(0)" ::: "memory");
        else          asm volatile("s_waitcnt vmcnt(8)" ::: "memory");
        __builtin_amdgcn_sched_barrier(0);
        __builtin_amdgcn_s_barrier();

        f32x4 accS[4];
        #pragma unroll
        for (int nf = 0; nf < 4; ++nf) accS[nf] = (f32x4)0.f;
        __builtin_amdgcn_s_setprio(1);
        #pragma unroll
        for (int kk = 0; kk < 8; ++kk) {
            half8 fb[4];
            #pragma unroll
            for (int nf = 0; nf < 4; ++nf) {
                int row = nf * 16 + fr;
                fb[nf] = *(const half8*)&Ks[cur][row * 256 + (((kk << 2) | fq) ^ (row & 7)) * 8];
            }
            #pragma unroll
            for (int nf = 0; nf < 4; ++nf)
                accS[nf] = __builtin_amdgcn_mfma_f32_16x16x32_f16(
                    qf[kk], fb[nf], accS[nf], 0, 0, 0);
        }
        __builtin_amdgcn_s_setprio(0);

        float pm[4];
        #pragma unroll
        for (int j = 0; j < 4; ++j)
            pm[j] = rowmax16(fmaxf(fmaxf(accS[0][j], accS[1][j]),
                                   fmaxf(accS[2][j], accS[3][j])));

        int chg = 0;
        #pragma unroll
        for (int j = 0; j < 4; ++j) chg |= (pm[j] > m_run[j]);
        if (__any(chg)) {   // exact defer: skip when max unchanged everywhere
            #pragma unroll
            for (int j = 0; j < 4; ++j) {
                float mn = fmaxf(m_run[j], pm[j]);
                float a = __expf(m_run[j] - mn);
                m_run[j] = mn;
                accL[j] *= a;
                #pragma unroll
                for (int nf = 0; nf < 16; ++nf) accO[nf][j] *= a;
            }
        }

        #pragma unroll
        for (int kkm = 0; kkm < 2; ++kkm) {
            #pragma unroll
            for (int j = 0; j < 4; ++j)
                #pragma unroll
                for (int nfh = 0; nfh < 2; ++nfh) {
                    float p = __expf(accS[kkm * 2 + nfh][j] - m_run[j]);
                    Ps[w][fq * 4 + j][nfh * 16 + fr] = f2h(p);
                }
            half8 fa = *(const half8*)&Ps[w][fr][fq * 8];
            accL = __builtin_amdgcn_mfma_f32_16x16x32_f16(fa, ones, accL, 0, 0, 0);
            __builtin_amdgcn_s_setprio(1);
            #pragma unroll
            for (int nf = 0; nf < 16; ++nf) {
                int row = nf * 16 + fr;
                half8 fbv = *(const half8*)&Vs[cur][row * 64 + (((kkm << 2) | fq) ^ (row & 7)) * 8];
                accO[nf] = __builtin_amdgcn_mfma_f32_16x16x32_f16(
                    fa, fbv, accO[nf], 0, 0, 0);
            }
            __builtin_amdgcn_s_setprio(0);
        }

        __builtin_amdgcn_s_barrier();
        if (mt < 14) STAGE_KV(cur, (mt + 2) * 64);
    }

    u16* yb = y + ((size_t)b * NS + n0 + w * 16) * CI;
    #pragma unroll
    for (int j = 0; j < 4; ++j) {
        float inv = 1.f / accL[j];
        int row = fq * 4 + j;
        #pragma unroll
        for (int nf = 0; nf < 16; ++nf)
            yb[(size_t)row * CI + nf * 16 + fr] = f2h(accO[nf][j] * inv);
    }
    #undef STAGE_KV
}

// ---------------------------------------------------------------------------
// bn_stats_part: block = (c, b) reads one contiguous 16KB z-row; deterministic
// partial {sum, sumsq} -> pS/pQ[c*8+b] (plain stores, replay-safe).
__global__ __launch_bounds__(256) void bn_stats_part(const u16* __restrict__ z,
                                                     float* __restrict__ pS,
                                                     float* __restrict__ pQ) {
    int c = blockIdx.x >> 3, b = blockIdx.x & 7;
    int t = threadIdx.x;
    const u16* p = z + ((size_t)b * CCH + c) * NS + t * 8;
    float s = 0.f, q = 0.f;
    #pragma unroll
    for (int i = 0; i < 4; ++i) {
        uint4 v = *(const uint4*)(p + i * 2048);
        const u16* u = (const u16*)&v;
        #pragma unroll
        for (int j = 0; j < 8; ++j) { float f = h2f(u[j]); s += f; q += f * f; }
    }
    #pragma unroll
    for (int off = 32; off; off >>= 1) { s += __shfl_xor(s, off); q += __shfl_xor(q, off); }
    __shared__ float rs[4], rq[4];
    int w = t >> 6;
    if ((t & 63) == 0) { rs[w] = s; rq[w] = q; }
    __syncthreads();
    if (t == 0) {
        pS[blockIdx.x] = rs[0] + rs[1] + rs[2] + rs[3];
        pQ[blockIdx.x] = rq[0] + rq[1] + rq[2] + rq[3];
    }
}

// stats_fin2: fold 8 partials per channel into mean/rstd
__global__ void stats_fin2(const float* __restrict__ pS, const float* __restrict__ pQ,
                           float* __restrict__ stats) {
    int c = blockIdx.x * 256 + threadIdx.x;
    if (c >= CCH) return;
    float s = 0.f, q = 0.f;
    #pragma unroll
    for (int b = 0; b < 8; ++b) { s += pS[c * 8 + b]; q += pQ[c * 8 + b]; }
    const float inv = 1.f / 65536.f;
    float mean = s * inv;
    float var = q * inv - mean * mean;
    stats[c] = mean;
    stats[CCH + c] = rsqrtf(var + 1e-5f);
}

// ---------------------------------------------------------------------------
// out = (z - mean)*rstd*gamma + beta + x   (8 elems/thread)
__global__ __launch_bounds__(256) void bn_final(const u16* __restrict__ z,
                                                const float* __restrict__ x,
                                                const float* __restrict__ stats,
                                                const float* __restrict__ gamma,
                                                const float* __restrict__ beta,
                                                float* __restrict__ out) {
    size_t i = ((size_t)blockIdx.x * 256 + threadIdx.x) * 8;
    int c = (int)((i >> 13) & 511);
    float g = gamma[c] * stats[CCH + c];
    float sh = beta[c] - stats[c] * g;
    uint4 zv = *(const uint4*)(z + i);
    const u16* u = (const u16*)&zv;
    float4 x0 = *(const float4*)(x + i);
    float4 x1 = *(const float4*)(x + i + 4);
    float4 o0, o1;
    o0.x = h2f(u[0]) * g + sh + x0.x;
    o0.y = h2f(u[1]) * g + sh + x0.y;
    o0.z = h2f(u[2]) * g + sh + x0.z;
    o0.w = h2f(u[3]) * g + sh + x0.w;
    o1.x = h2f(u[4]) * g + sh + x1.x;
    o1.y = h2f(u[5]) * g + sh + x1.y;
    o1.z = h2f(u[6]) * g + sh + x1.z;
    o1.w = h2f(u[7]) * g + sh + x1.w;
    *(float4*)(out + i) = o0;
    *(float4*)(out + i + 4) = o1;
}

// ---------------------------------------------------------------------------
extern "C" void kernel_launch(void* const* d_in, const int* in_sizes, int n_in,
                              void* d_out, int out_size, void* d_ws, size_t ws_size,
                              hipStream_t stream) {
    const float* x       = (const float*)d_in[0];
    const float* theta_w = (const float*)d_in[1];
    const float* theta_b = (const float*)d_in[2];
    const float* phi_w   = (const float*)d_in[3];
    const float* phi_b   = (const float*)d_in[4];
    const float* g_w     = (const float*)d_in[5];
    const float* g_b     = (const float*)d_in[6];
    const float* wz_w    = (const float*)d_in[7];
    const float* wz_b    = (const float*)d_in[8];
    const float* gamma   = (const float*)d_in[9];
    const float* beta    = (const float*)d_in[10];

    char* base = (char*)d_ws;
    u16*   W3b   = (u16*)base;                             // 786432 B
    float* b3    = (float*)(base + 786432);                // 3072 B
    u16*   wzb   = (u16*)(base + 789504);                  // 262144 B
    float* stats = (float*)(base + 1051648);               // 4096 B
    float* pS    = (float*)(base + 1055744);               // 16 KB
    float* pQ    = (float*)(base + 1072128);               // 16 KB
    u16*   projq = (u16*)(base + 1088512);                 // 33.6 MB
    u16*   P1    = (u16*)(base + 1088512 + 33554432);      // 16.8 MB
    u16*   kb    = (u16*)(base + 1088512 + 50331648);      // 4 MB
    u16*   vg    = (u16*)(base + 1088512 + 54525952);      // 4 MB
    u16*   xt    = (u16*)(base + 1088512 + 58720256);      // 67.1 MB
    u16*   y     = (u16*)(base + 1088512 + 125829120);     // 33.6 MB
    u16*   z     = (u16*)(base + 1088512 + 159383552);     // 67.1 MB

    // 1) weights
    prep_w<<<2048, 256, 0, stream>>>(theta_w, theta_b, phi_w, phi_b, g_w, g_b,
                                     wz_w, W3b, b3, wzb);
    // 2) x -> xt (fp16, [b][n][c])
    transpose_x<<<dim3(64, 8, 8), 256, 0, stream>>>(x, xt);

    // 3) proj + fused hw-pool: projq[b][n][256], P1[b][2048][512]
    proj_gemm<<<dim3(6, 64, 8), 256, 0, stream>>>(xt, W3b, b3, projq, P1);

    // 4) pool2 (coalesced both sides): kb[b][m][ci], vg[b][ci][m]
    pool2_kernel<<<128, 256, 0, stream>>>(P1, kb, vg);

    // 5) fused attention -> y[b][n][ci]
    attn_fused<<<dim3(64, 8), 512, 0, stream>>>(projq, kb, vg, y);

    // 6) z[b][c][n] = wzb * y^T + wz_b(row)
    gemm_nt_f16<1><<<dim3(64, 4, 8), 256, 0, stream>>>(
        wzb, y, z, wz_b, CI, CI, NS, CI,
        0, (size_t)NS * CI, (size_t)CCH * NS);

    // 7) BN stats: 4096-block partials + tiny finalize
    bn_stats_part<<<4096, 256, 0, stream>>>(z, pS, pQ);
    stats_fin2<<<2, 256, 0, stream>>>(pS, pQ, stats);

    // 8) normalize + residual
    bn_final<<<16384, 256, 0, stream>>>(z, x, stats, gamma, beta, (float*)d_out);
}

// Round 19
// 335.005 us; speedup vs baseline: 1.0280x; 1.0280x over previous
//
#include <hip/hip_runtime.h>
#include <math.h>

typedef unsigned short u16;
typedef __attribute__((ext_vector_type(8))) _Float16 half8;
typedef __attribute__((ext_vector_type(4))) float f32x4;

#define NS 8192
#define MS 1024
#define CCH 512
#define CI 256
#define O3 768

// ---- fp16 helpers (bit-level storage as u16) ----
__device__ __forceinline__ float h2f(u16 u) {
    _Float16 h; *(u16*)&h = u; return (float)h;
}
__device__ __forceinline__ u16 f2h(float f) {
    _Float16 h = (_Float16)f; return *(u16*)&h;
}

// async global->LDS 16B
__device__ __forceinline__ void gld16(u16* lds, const u16* g) {
    __builtin_amdgcn_global_load_lds((const __attribute__((address_space(1))) void*)g,
                                     (__attribute__((address_space(3))) void*)lds,
                                     16, 0, 0);
}

// VALU cross-lane max via DPP (no LDS pipe). Butterfly covers 16-lane group.
template<int CTRL>
__device__ __forceinline__ float dppmax(float x) {
    union { float f; int i; } a, b;
    a.f = x;
    b.i = __builtin_amdgcn_update_dpp(a.i, a.i, CTRL, 0xF, 0xF, false);
    return fmaxf(a.f, b.f);
}
__device__ __forceinline__ float rowmax16(float x) {
    x = dppmax<0xB1>(x);     // quad_perm [1,0,3,2]
    x = dppmax<0x4E>(x);     // quad_perm [2,3,0,1]
    x = dppmax<0x141>(x);    // row_half_mirror
    x = dppmax<0x140>(x);    // row_mirror
    return x;
}

// ---------------------------------------------------------------------------
// prep: concat+convert weights to fp16
__global__ void prep_w(const float* __restrict__ tw, const float* __restrict__ tb,
                       const float* __restrict__ pw, const float* __restrict__ pb,
                       const float* __restrict__ gw, const float* __restrict__ gb,
                       const float* __restrict__ wzw,
                       u16* __restrict__ W3b, float* __restrict__ b3, u16* __restrict__ wzb) {
    int i = blockIdx.x * 256 + threadIdx.x;
    if (i < O3 * CCH) {
        int o = i >> 9, c = i & 511;
        float v = (o < 256) ? tw[o * 512 + c] : (o < 512) ? pw[(o - 256) * 512 + c]
                                              : gw[(o - 512) * 512 + c];
        W3b[i] = f2h(v);
    } else {
        int j = i - O3 * CCH;
        if (j < CCH * CI) wzb[j] = f2h(wzw[j]);
    }
    if (i < O3) b3[i] = (i < 256) ? tb[i] : (i < 512) ? pb[i - 256] : gb[i - 512];
}

// ---------------------------------------------------------------------------
// transpose x[b][c][n] fp32 -> xt[b][n][c] fp16   (tile 64c x 128n)
__global__ __launch_bounds__(256) void transpose_x(const float* __restrict__ x,
                                                   u16* __restrict__ xt) {
    __shared__ float tile[64][129];
    int b = blockIdx.z;
    int n0 = blockIdx.x * 128, c0 = blockIdx.y * 64;
    const float* xb = x + ((size_t)b * CCH + c0) * NS + n0;
    int t = threadIdx.x;
    #pragma unroll
    for (int i = 0; i < 32; ++i) {
        int idx = t + i * 256;
        int c = idx >> 7, n = idx & 127;
        tile[c][n] = xb[(size_t)c * NS + n];
    }
    __syncthreads();
    u16* xo = xt + ((size_t)b * NS + n0) * CCH + c0;
    #pragma unroll
    for (int i = 0; i < 16; ++i) {
        int idx = t + i * 256;
        int cp = idx & 31, n = idx >> 5;
        unsigned lo = f2h(tile[2 * cp][n]);
        unsigned hi = f2h(tile[2 * cp + 1][n]);
        *(unsigned*)(xo + (size_t)n * CCH + 2 * cp) = lo | (hi << 16);
    }
}

// ---------------------------------------------------------------------------
// proj GEMM with fused partial-pool epilogue (R12-proven, 256 threads).
// bx 0..1 (theta cols 0..255): dense write to projq[b][n][256].
// bx 2..5 (phi/g cols 256..767): 2x2 h/w max-pool in-register -> P1.
__global__ __launch_bounds__(256) void proj_gemm(
        const u16* __restrict__ A, const u16* __restrict__ Bm,
        const float* __restrict__ bias,
        u16* __restrict__ projq, u16* __restrict__ P1) {
    __shared__ u16 As[2][128 * 64];
    __shared__ u16 Bs[2][128 * 64];
    const int t = threadIdx.x;
    const int l = t & 63, w = t >> 6;
    const int wr = w >> 1, wc = w & 1;
    const int fr = l & 15, fq = l >> 4;

    const int nx = gridDim.x, ny = gridDim.y;
    int bid = blockIdx.x + nx * (blockIdx.y + ny * blockIdx.z);
    int cpx = (nx * ny * (int)gridDim.z) >> 3;
    int Wd = (bid & 7) * cpx + (bid >> 3);
    int bx = Wd % nx, rem = Wd / nx;
    int by = rem % ny, bz = rem / ny;

    const u16* gA = A + (size_t)bz * NS * CCH + (size_t)(by * 128) * CCH;
    const u16* gB = Bm + (size_t)(bx * 128) * CCH;

    f32x4 acc[4][4];
    #pragma unroll
    for (int m = 0; m < 4; ++m)
        #pragma unroll
        for (int n = 0; n < 4; ++n) acc[m][n] = (f32x4)0.f;

    #define STAGE_AB(buf, k0)                                                 \
        {                                                                     \
            _Pragma("unroll")                                                 \
            for (int i = 0; i < 4; ++i) {                                     \
                int cd = t + i * 256;                                         \
                int row = cd >> 3;                                            \
                int k8 = ((cd & 7) ^ (row & 7)) * 8;                          \
                int lbase = (cd & ~63) * 8;                                   \
                gld16(&As[buf][lbase], gA + (size_t)row * CCH + (k0) + k8);   \
                gld16(&Bs[buf][lbase], gB + (size_t)row * CCH + (k0) + k8);   \
            }                                                                 \
        }

    const int nk = CCH >> 6;   // 8
    STAGE_AB(0, 0);
    STAGE_AB(1, 64);

    for (int mt = 0; mt < nk; ++mt) {
        const int cur = mt & 1;
        if (mt == nk - 1) asm volatile("s_waitcnt vmcnt(0)" ::: "memory");
        else              asm volatile("s_waitcnt vmcnt(8)" ::: "memory");
        __builtin_amdgcn_sched_barrier(0);
        __builtin_amdgcn_s_barrier();

        half8 fa[4][2], fb[4][2];
        #pragma unroll
        for (int m = 0; m < 4; ++m)
            #pragma unroll
            for (int kk = 0; kk < 2; ++kk) {
                int ra = wr * 64 + m * 16 + fr;
                int rb = wc * 64 + m * 16 + fr;
                fa[m][kk] = *(const half8*)&As[cur][ra * 64 + ((((kk << 2) | fq)) ^ (ra & 7)) * 8];
                fb[m][kk] = *(const half8*)&Bs[cur][rb * 64 + ((((kk << 2) | fq)) ^ (rb & 7)) * 8];
            }
        __builtin_amdgcn_s_setprio(1);
        #pragma unroll
        for (int kk = 0; kk < 2; ++kk)
            #pragma unroll
            for (int m = 0; m < 4; ++m)
                #pragma unroll
                for (int n = 0; n < 4; ++n)
                    acc[m][n] = __builtin_amdgcn_mfma_f32_16x16x32_f16(
                        fa[m][kk], fb[n][kk], acc[m][n], 0, 0, 0);
        __builtin_amdgcn_s_setprio(0);

        __builtin_amdgcn_s_barrier();
        if (mt + 2 < nk) STAGE_AB(cur, (mt + 2) * 64);
    }
    #undef STAGE_AB

    const int ccol0 = bx * 128 + wc * 64;
    if (ccol0 < 256) {
        // theta: dense write projq[b][n][256]
        u16* gC = projq + (size_t)bz * NS * 256;
        const int crow0 = by * 128 + wr * 64;
        #pragma unroll
        for (int m = 0; m < 4; ++m)
            #pragma unroll
            for (int n = 0; n < 4; ++n) {
                int col = ccol0 + n * 16 + fr;
                float cb = bias[col];
                #pragma unroll
                for (int j = 0; j < 4; ++j) {
                    int row = crow0 + m * 16 + fq * 4 + j;
                    gC[(size_t)row * 256 + col] = f2h(acc[m][n][j] + cb);
                }
            }
    } else {
        // phi/g: 2x2 h/w-pool in-register -> P1[b][tt*256+h2*16+w2][c1]
        int tt = by >> 3;
        int h2 = ((by & 7) << 1) + wr;
        u16* gP = P1 + ((size_t)bz * 2048 + tt * 256 + h2 * 16) * 512;
        #pragma unroll
        for (int mh = 0; mh < 2; ++mh)
            #pragma unroll
            for (int n = 0; n < 4; ++n) {
                int col = ccol0 + n * 16 + fr;
                float cb = bias[col];
                int c1 = col - 256;
                #pragma unroll
                for (int jj = 0; jj < 2; ++jj) {
                    float mx = fmaxf(
                        fmaxf(acc[mh][n][2 * jj], acc[mh][n][2 * jj + 1]),
                        fmaxf(acc[mh + 2][n][2 * jj], acc[mh + 2][n][2 * jj + 1]));
                    int w2 = mh * 8 + fq * 2 + jj;
                    gP[(size_t)w2 * 512 + c1] = f2h(mx + cb);
                }
            }
    }
}

// ---------------------------------------------------------------------------
// pool2: finish t-pair max from P1 -> kb[b][m][ci], vg[b][ci][m] (coalesced)
__global__ __launch_bounds__(256) void pool2_kernel(const u16* __restrict__ P1,
                                                    u16* __restrict__ kb,
                                                    u16* __restrict__ vg) {
    int bid = blockIdx.x;                  // 8 * 4 * 4 = 128 blocks
    int b = bid >> 4, tp = (bid >> 2) & 3, hw0 = (bid & 3) * 64;
    int t = threadIdx.x;
    const u16* p0 = P1 + ((size_t)b * 2048 + (2 * tp) * 256 + hw0) * 512;
    const u16* p1 = p0 + 256 * 512;
    u16* kbb = kb + ((size_t)b * MS + tp * 256 + hw0) * CI + t;
    unsigned pack[32];
    #pragma unroll
    for (int mm = 0; mm < 64; ++mm) {
        size_t ro = (size_t)mm * 512;
        float kv = fmaxf(h2f(p0[ro + t]), h2f(p1[ro + t]));
        float vv = fmaxf(h2f(p0[ro + 256 + t]), h2f(p1[ro + 256 + t]));
        kbb[(size_t)mm * CI] = f2h(kv);
        unsigned hv = f2h(vv);
        if (mm & 1) pack[mm >> 1] |= hv << 16;
        else        pack[mm >> 1] = hv;
    }
    u16* dst = vg + ((size_t)b * CI + t) * MS + tp * 256 + hw0;
    #pragma unroll
    for (int i = 0; i < 8; ++i)
        *(uint4*)(dst + i * 8) = *(const uint4*)&pack[i * 4];
}

// ---------------------------------------------------------------------------
// NT GEMM (fp16, MFMA) — Wz stage (R12-proven). dbuf + counted vmcnt + T2.
// BIAS_MODE: 0 none, 1 by-row (fp32), 2 by-col (fp32)
template<int BIAS_MODE>
__global__ __launch_bounds__(256) void gemm_nt_f16(
        const u16* __restrict__ A, const u16* __restrict__ Bm,
        u16* __restrict__ C, const float* __restrict__ bias,
        int lda, int ldb, int ldc, int Ksize,
        size_t strideA, size_t strideB, size_t strideC) {
    __shared__ u16 As[2][128 * 64];
    __shared__ u16 Bs[2][128 * 64];
    const int t = threadIdx.x;
    const int l = t & 63, w = t >> 6;
    const int wr = w >> 1, wc = w & 1;
    const int fr = l & 15, fq = l >> 4;

    const int nx = gridDim.x, ny = gridDim.y;
    int bid = blockIdx.x + nx * (blockIdx.y + ny * blockIdx.z);
    int cpx = (nx * ny * (int)gridDim.z) >> 3;
    int Wd = (bid & 7) * cpx + (bid >> 3);
    int bx = Wd % nx, rem = Wd / nx;
    int by = rem % ny, bz = rem / ny;

    const u16* gA = A + (size_t)bz * strideA + (size_t)(by * 128) * lda;
    const u16* gB = Bm + (size_t)bz * strideB + (size_t)(bx * 128) * ldb;

    f32x4 acc[4][4];
    #pragma unroll
    for (int m = 0; m < 4; ++m)
        #pragma unroll
        for (int n = 0; n < 4; ++n) acc[m][n] = (f32x4)0.f;

    #define STAGE_AB(buf, k0)                                                 \
        {                                                                     \
            _Pragma("unroll")                                                 \
            for (int i = 0; i < 4; ++i) {                                     \
                int cd = t + i * 256;                                         \
                int row = cd >> 3;                                            \
                int k8 = ((cd & 7) ^ (row & 7)) * 8;                          \
                int lbase = (cd & ~63) * 8;                                   \
                gld16(&As[buf][lbase], gA + (size_t)row * lda + (k0) + k8);   \
                gld16(&Bs[buf][lbase], gB + (size_t)row * ldb + (k0) + k8);   \
            }                                                                 \
        }

    const int nk = Ksize >> 6;
    STAGE_AB(0, 0);
    STAGE_AB(1, 64);

    for (int mt = 0; mt < nk; ++mt) {
        const int cur = mt & 1;
        if (mt == nk - 1) asm volatile("s_waitcnt vmcnt(0)" ::: "memory");
        else              asm volatile("s_waitcnt vmcnt(8)" ::: "memory");
        __builtin_amdgcn_sched_barrier(0);
        __builtin_amdgcn_s_barrier();

        half8 fa[4][2], fb[4][2];
        #pragma unroll
        for (int m = 0; m < 4; ++m)
            #pragma unroll
            for (int kk = 0; kk < 2; ++kk) {
                int ra = wr * 64 + m * 16 + fr;
                int rb = wc * 64 + m * 16 + fr;
                fa[m][kk] = *(const half8*)&As[cur][ra * 64 + ((((kk << 2) | fq)) ^ (ra & 7)) * 8];
                fb[m][kk] = *(const half8*)&Bs[cur][rb * 64 + ((((kk << 2) | fq)) ^ (rb & 7)) * 8];
            }
        __builtin_amdgcn_s_setprio(1);
        #pragma unroll
        for (int kk = 0; kk < 2; ++kk)
            #pragma unroll
            for (int m = 0; m < 4; ++m)
                #pragma unroll
                for (int n = 0; n < 4; ++n)
                    acc[m][n] = __builtin_amdgcn_mfma_f32_16x16x32_f16(
                        fa[m][kk], fb[n][kk], acc[m][n], 0, 0, 0);
        __builtin_amdgcn_s_setprio(0);

        __builtin_amdgcn_s_barrier();
        if (mt + 2 < nk) STAGE_AB(cur, (mt + 2) * 64);
    }
    #undef STAGE_AB

    u16* gC = C + (size_t)bz * strideC;
    const int crow0 = by * 128 + wr * 64;
    const int ccol0 = bx * 128 + wc * 64;
    #pragma unroll
    for (int m = 0; m < 4; ++m) {
        #pragma unroll
        for (int n = 0; n < 4; ++n) {
            int col = ccol0 + n * 16 + fr;
            float cb = (BIAS_MODE == 2) ? bias[col] : 0.f;
            #pragma unroll
            for (int j = 0; j < 4; ++j) {
                int row = crow0 + m * 16 + fq * 4 + j;
                float v = acc[m][n][j] + cb;
                if (BIAS_MODE == 1) v += bias[row];
                gC[(size_t)row * ldc + col] = f2h(v);
            }
        }
    }
}

// ---------------------------------------------------------------------------
// Fused flash attention: 8 waves x 16 q-rows, m-tile 64, K/V dbuf, counted
// vmcnt, raw barriers, DPP max, ones-MFMA row-sums, T13 defer-max (THR=8).
__global__ __launch_bounds__(512, 2) void attn_fused(
        const u16* __restrict__ projq, const u16* __restrict__ kb,
        const u16* __restrict__ vg, u16* __restrict__ y) {
    __shared__ u16 Ks[2][64 * 256];     // 2 x 32 KB
    __shared__ u16 Vs[2][256 * 64];     // 2 x 32 KB
    __shared__ u16 Ps[8][16][40];       // 10 KB

    int bid0 = blockIdx.x + 64 * blockIdx.y;
    int W = (bid0 & 7) * 64 + (bid0 >> 3);
    const int b = W >> 6;
    const int n0 = (W & 63) * 128;

    const int t = threadIdx.x;
    const int l = t & 63, w = t >> 6;
    const int fr = l & 15, fq = l >> 4;

    const u16* projb = projq + (size_t)b * NS * 256;
    const u16* kbb = kb + (size_t)b * MS * CI;
    const u16* vgb = vg + (size_t)b * CI * MS;

    half8 qf[8];
    {
        const u16* qrow = projb + (size_t)(n0 + w * 16 + fr) * 256 + fq * 8;
        #pragma unroll
        for (int kk = 0; kk < 8; ++kk)
            qf[kk] = *(const half8*)(qrow + kk * 32);
    }

    half8 ones;
    #pragma unroll
    for (int i = 0; i < 8; ++i) ones[i] = (_Float16)1.f;

    f32x4 accO[16];
    #pragma unroll
    for (int nf = 0; nf < 16; ++nf) accO[nf] = (f32x4)0.f;
    f32x4 accL = (f32x4)0.f;            // row sums via ones-MFMA
    float m_run[4];
    #pragma unroll
    for (int j = 0; j < 4; ++j) m_run[j] = -1e30f;

    #define STAGE_KV(buf, m0)                                                     \
        {                                                                         \
            _Pragma("unroll")                                                     \
            for (int i = 0; i < 4; ++i) {                                         \
                int c = t + i * 512;                                              \
                int lb = (c & ~63) << 3;                                          \
                int krow = c >> 5, kk8 = c & 31;                                  \
                gld16(&Ks[buf][lb],                                               \
                      kbb + (size_t)((m0) + krow) * CI + ((kk8 ^ (krow & 7)) << 3)); \
                int vrow = c >> 3, vk8 = c & 7;                                   \
                gld16(&Vs[buf][lb],                                               \
                      vgb + (size_t)vrow * MS + (m0) + ((vk8 ^ (vrow & 7)) << 3)); \
            }                                                                     \
        }

    STAGE_KV(0, 0);
    STAGE_KV(1, 64);

    for (int mt = 0; mt < 16; ++mt) {
        const int cur = mt & 1;
        if (mt == 15) asm volatile("s_waitcnt vmcnt(0)" ::: "memory");
        else          asm volatile("s_waitcnt vmcnt(8)" ::: "memory");
        __builtin_amdgcn_sched_barrier(0);
        __builtin_amdgcn_s_barrier();

        f32x4 accS[4];
        #pragma unroll
        for (int nf = 0; nf < 4; ++nf) accS[nf] = (f32x4)0.f;
        __builtin_amdgcn_s_setprio(1);
        #pragma unroll
        for (int kk = 0; kk < 8; ++kk) {
            half8 fb[4];
            #pragma unroll
            for (int nf = 0; nf < 4; ++nf) {
                int row = nf * 16 + fr;
                fb[nf] = *(const half8*)&Ks[cur][row * 256 + (((kk << 2) | fq) ^ (row & 7)) * 8];
            }
            #pragma unroll
            for (int nf = 0; nf < 4; ++nf)
                accS[nf] = __builtin_amdgcn_mfma_f32_16x16x32_f16(
                    qf[kk], fb[nf], accS[nf], 0, 0, 0);
        }
        __builtin_amdgcn_s_setprio(0);

        float pm[4];
        #pragma unroll
        for (int j = 0; j < 4; ++j)
            pm[j] = rowmax16(fmaxf(fmaxf(accS[0][j], accS[1][j]),
                                   fmaxf(accS[2][j], accS[3][j])));

        // T13 defer-max: only rescale when max grew by more than THR=8;
        // P is then bounded by e^8 (fp16-safe), scale divides out in O/l.
        int chg = 0;
        #pragma unroll
        for (int j = 0; j < 4; ++j) chg |= (pm[j] > m_run[j] + 8.f);
        if (__any(chg)) {
            #pragma unroll
            for (int j = 0; j < 4; ++j) {
                float mn = fmaxf(m_run[j], pm[j]);
                float a = __expf(m_run[j] - mn);
                m_run[j] = mn;
                accL[j] *= a;
                #pragma unroll
                for (int nf = 0; nf < 16; ++nf) accO[nf][j] *= a;
            }
        }

        #pragma unroll
        for (int kkm = 0; kkm < 2; ++kkm) {
            #pragma unroll
            for (int j = 0; j < 4; ++j)
                #pragma unroll
                for (int nfh = 0; nfh < 2; ++nfh) {
                    float p = __expf(accS[kkm * 2 + nfh][j] - m_run[j]);
                    Ps[w][fq * 4 + j][nfh * 16 + fr] = f2h(p);
                }
            half8 fa = *(const half8*)&Ps[w][fr][fq * 8];
            accL = __builtin_amdgcn_mfma_f32_16x16x32_f16(fa, ones, accL, 0, 0, 0);
            __builtin_amdgcn_s_setprio(1);
            #pragma unroll
            for (int nf = 0; nf < 16; ++nf) {
                int row = nf * 16 + fr;
                half8 fbv = *(const half8*)&Vs[cur][row * 64 + (((kkm << 2) | fq) ^ (row & 7)) * 8];
                accO[nf] = __builtin_amdgcn_mfma_f32_16x16x32_f16(
                    fa, fbv, accO[nf], 0, 0, 0);
            }
            __builtin_amdgcn_s_setprio(0);
        }

        __builtin_amdgcn_s_barrier();
        if (mt < 14) STAGE_KV(cur, (mt + 2) * 64);
    }

    u16* yb = y + ((size_t)b * NS + n0 + w * 16) * CI;
    #pragma unroll
    for (int j = 0; j < 4; ++j) {
        float inv = 1.f / accL[j];
        int row = fq * 4 + j;
        #pragma unroll
        for (int nf = 0; nf < 16; ++nf)
            yb[(size_t)row * CI + nf * 16 + fr] = f2h(accO[nf][j] * inv);
    }
    #undef STAGE_KV
}

// ---------------------------------------------------------------------------
// BN stats over z[b][c][n] fp16: one block per channel (R17-proven)
__global__ __launch_bounds__(256) void bn_stats(const u16* __restrict__ z,
                                                float* __restrict__ stats) {
    int c = blockIdx.x, t = threadIdx.x;
    float s = 0.f, q = 0.f;
    for (int b = 0; b < 8; ++b) {
        const u16* p = z + ((size_t)b * CCH + c) * NS;
        #pragma unroll
        for (int i = 0; i < 4; ++i) {
            uint4 v = *(const uint4*)(p + (t + i * 256) * 8);
            const u16* u = (const u16*)&v;
            #pragma unroll
            for (int j = 0; j < 8; ++j) { float f = h2f(u[j]); s += f; q += f * f; }
        }
    }
    #pragma unroll
    for (int off = 32; off; off >>= 1) { s += __shfl_xor(s, off); q += __shfl_xor(q, off); }
    __shared__ float rs[4], rq[4];
    int w = t >> 6;
    if ((t & 63) == 0) { rs[w] = s; rq[w] = q; }
    __syncthreads();
    if (t == 0) {
        float S2 = rs[0] + rs[1] + rs[2] + rs[3];
        float Q = rq[0] + rq[1] + rq[2] + rq[3];
        const float inv = 1.f / 65536.f;
        float mean = S2 * inv;
        float var = Q * inv - mean * mean;
        stats[c] = mean;
        stats[CCH + c] = rsqrtf(var + 1e-5f);
    }
}

// ---------------------------------------------------------------------------
// out = (z - mean)*rstd*gamma + beta + x   (8 elems/thread)
__global__ __launch_bounds__(256) void bn_final(const u16* __restrict__ z,
                                                const float* __restrict__ x,
                                                const float* __restrict__ stats,
                                                const float* __restrict__ gamma,
                                                const float* __restrict__ beta,
                                                float* __restrict__ out) {
    size_t i = ((size_t)blockIdx.x * 256 + threadIdx.x) * 8;
    int c = (int)((i >> 13) & 511);
    float g = gamma[c] * stats[CCH + c];
    float sh = beta[c] - stats[c] * g;
    uint4 zv = *(const uint4*)(z + i);
    const u16* u = (const u16*)&zv;
    float4 x0 = *(const float4*)(x + i);
    float4 x1 = *(const float4*)(x + i + 4);
    float4 o0, o1;
    o0.x = h2f(u[0]) * g + sh + x0.x;
    o0.y = h2f(u[1]) * g + sh + x0.y;
    o0.z = h2f(u[2]) * g + sh + x0.z;
    o0.w = h2f(u[3]) * g + sh + x0.w;
    o1.x = h2f(u[4]) * g + sh + x1.x;
    o1.y = h2f(u[5]) * g + sh + x1.y;
    o1.z = h2f(u[6]) * g + sh + x1.z;
    o1.w = h2f(u[7]) * g + sh + x1.w;
    *(float4*)(out + i) = o0;
    *(float4*)(out + i + 4) = o1;
}

// ---------------------------------------------------------------------------
extern "C" void kernel_launch(void* const* d_in, const int* in_sizes, int n_in,
                              void* d_out, int out_size, void* d_ws, size_t ws_size,
                              hipStream_t stream) {
    const float* x       = (const float*)d_in[0];
    const float* theta_w = (const float*)d_in[1];
    const float* theta_b = (const float*)d_in[2];
    const float* phi_w   = (const float*)d_in[3];
    const float* phi_b   = (const float*)d_in[4];
    const float* g_w     = (const float*)d_in[5];
    const float* g_b     = (const float*)d_in[6];
    const float* wz_w    = (const float*)d_in[7];
    const float* wz_b    = (const float*)d_in[8];
    const float* gamma   = (const float*)d_in[9];
    const float* beta    = (const float*)d_in[10];

    char* base = (char*)d_ws;
    u16*   W3b   = (u16*)base;                             // 786432 B
    float* b3    = (float*)(base + 786432);                // 3072 B
    u16*   wzb   = (u16*)(base + 789504);                  // 262144 B
    float* stats = (float*)(base + 1051648);               // 4096 B
    u16*   projq = (u16*)(base + 1056768);                 // 33.6 MB
    u16*   P1    = (u16*)(base + 1056768 + 33554432);      // 16.8 MB
    u16*   kb    = (u16*)(base + 1056768 + 50331648);      // 4 MB
    u16*   vg    = (u16*)(base + 1056768 + 54525952);      // 4 MB
    u16*   xt    = (u16*)(base + 1056768 + 58720256);      // 67.1 MB
    u16*   y     = (u16*)(base + 1056768 + 125829120);     // 33.6 MB
    u16*   z     = (u16*)(base + 1056768 + 159383552);     // 67.1 MB

    // 1) weights
    prep_w<<<2048, 256, 0, stream>>>(theta_w, theta_b, phi_w, phi_b, g_w, g_b,
                                     wz_w, W3b, b3, wzb);
    // 2) x -> xt (fp16, [b][n][c])
    transpose_x<<<dim3(64, 8, 8), 256, 0, stream>>>(x, xt);

    // 3) proj + fused hw-pool: projq[b][n][256], P1[b][2048][512]
    proj_gemm<<<dim3(6, 64, 8), 256, 0, stream>>>(xt, W3b, b3, projq, P1);

    // 4) pool2 (coalesced both sides): kb[b][m][ci], vg[b][ci][m]
    pool2_kernel<<<128, 256, 0, stream>>>(P1, kb, vg);

    // 5) fused attention -> y[b][n][ci]
    attn_fused<<<dim3(64, 8), 512, 0, stream>>>(projq, kb, vg, y);

    // 6) z[b][c][n] = wzb * y^T + wz_b(row)
    gemm_nt_f16<1><<<dim3(64, 4, 8), 256, 0, stream>>>(
        wzb, y, z, wz_b, CI, CI, NS, CI,
        0, (size_t)NS * CI, (size_t)CCH * NS);

    // 7) BN stats
    bn_stats<<<CCH, 256, 0, stream>>>(z, stats);

    // 8) normalize + residual
    bn_final<<<16384, 256, 0, stream>>>(z, x, stats, gamma, beta, (float*)d_out);
}